// Round 4
// baseline (306.713 us; speedup 1.0000x reference)
//
#include <hip/hip_runtime.h>
#include <hip/hip_bf16.h>
#include <math.h>

// Problem constants
#define FPD 96      // frame size
#define DPD 28      // digit/kernel size
#define CPD 69      // FPD - DPD + 1
#define NPD 4761    // CPD*CPD
#define KKC 3       // K iterations
#define SBN 256     // S*B images
#define TT 8        // T
#define HD 512      // H
#define ZDD 2
#define KPAD 4768   // 149*32, padded K for MFMA GEMM
#define SPLITK 15
#define FRSH 104    // frame LDS row stride (halfs): 52 words, mod32=20 -> conflict-free
#define CVS 76      // cv slab row stride (floats): mod32=12 -> conflict-free

typedef __attribute__((ext_vector_type(8))) short bf16x8;
typedef __attribute__((ext_vector_type(4))) float f32x4;
typedef _Float16 half_t;
typedef __attribute__((ext_vector_type(2))) _Float16 half2_t;

__device__ __forceinline__ float bf2f_lo(unsigned int u) {
    union { unsigned int i; float f; } v; v.i = u << 16; return v.f;
}
__device__ __forceinline__ float bf2f_hi(unsigned int u) {
    union { unsigned int i; float f; } v; v.i = u & 0xffff0000u; return v.f;
}
__device__ __forceinline__ half2_t u2h(unsigned int u) {
    union { unsigned int i; half2_t h; } v; v.i = u; return v.h;
}

// Conv-phase LDS block (~106.4 KB -> 1 block/CU for kernels containing it).
struct ConvLds {
    half_t fr[96 * FRSH];
    half_t kr[28 * 32];   // rows padded to 32 halfs
    float  dg[784];
    float  cv[4][69 * CVS];
    float  red[32];
};

struct MlpLds {
    float hsh[HD];
    float h2[2][256];
    float res_sh[2][2];
};

// ---------------------------------------------------------------------------
// Conv (f16 dot2) + fused recon-subtract + softmax-exp (bf16 out).
// 1024 threads, one image per block. Verified body (301 us baseline / mega).
__device__ __forceinline__ void conv_phase(
    ConvLds& L, int k, int ib, int t,
    const float* __restrict__ frames, const int* __restrict__ tsp,
    float* __restrict__ frameL, const float* __restrict__ ck,
    float zx, float zy,
    ushort* __restrict__ e_buf, float* __restrict__ inv_denom)
{
    half_t* fr  = L.fr;
    half_t* kr  = L.kr;
    float*  dg  = L.dg;
    float*  red = L.red;

    if (t < 28 * 32) {
        int dy = t >> 5, dx = t & 31;
        float v = (dx < 28) ? ck[((size_t)ib * KKC + k) * 784 + dy * 28 + dx] : 0.f;
        kr[t] = (half_t)v;
    }
    if (k > 0 && t < 784) dg[t] = ck[((size_t)ib * KKC + (k - 1)) * 784 + t];
    __syncthreads();

    const float* src = (k < 2)
        ? frames + ((size_t)ib * TT + *tsp) * 9216
        : frameL + (size_t)ib * 9216;
    const float scale = 96.f / 28.f;
    for (int p = t; p < 9216; p += 1024) {
        int r = p / 96, c = p - r * 96;
        float val = src[p];
        if (k > 0) {
            float oci = (2.f * r + 1.f) / 96.f - 1.f;
            float ocj = (2.f * c + 1.f) / 96.f - 1.f;
            float py = ((scale * (oci - zy) + 1.f) * 28.f - 1.f) * 0.5f;
            float px = ((scale * (ocj - zx) + 1.f) * 28.f - 1.f) * 0.5f;
            float py0f = floorf(py), px0f = floorf(px);
            float fy = py - py0f, fx = px - px0f;
            int y0 = (int)py0f, x0 = (int)px0f;
            int y1 = y0 + 1, x1 = x0 + 1;
            float wy0 = (y0 >= 0 && y0 < DPD) ? 1.f - fy : 0.f;
            float wy1 = (y1 >= 0 && y1 < DPD) ? fy : 0.f;
            float wx0 = (x0 >= 0 && x0 < DPD) ? 1.f - fx : 0.f;
            float wx1 = (x1 >= 0 && x1 < DPD) ? fx : 0.f;
            int y0c = min(max(y0, 0), DPD - 1), y1c = min(max(y1, 0), DPD - 1);
            int x0c = min(max(x0, 0), DPD - 1), x1c = min(max(x1, 0), DPD - 1);
            float tmp0 = wy0 * dg[y0c * DPD + x0c] + wy1 * dg[y1c * DPD + x0c];
            float tmp1 = wy0 * dg[y0c * DPD + x1c] + wy1 * dg[y1c * DPD + x1c];
            val -= wx0 * tmp0 + wx1 * tmp1;
        }
        fr[r * FRSH + c] = (half_t)val;
        if (k == 1) frameL[(size_t)ib * 9216 + p] = val;
    }
    if (t < 96 * 8) fr[(t >> 3) * FRSH + 96 + (t & 7)] = (half_t)0.f; // pad cols
    __syncthreads();

    if (t < 828) {
        const int q    = t / 207;
        const int rem  = t - q * 207;
        const int tile = rem / 69;
        const int oy   = rem - tile * 69;
        const int ox0  = tile * 24;
        const int dy0  = q * 7;

        float acc[24];
        #pragma unroll
        for (int j = 0; j < 24; ++j) acc[j] = 0.f;

        #pragma unroll 1
        for (int dd = 0; dd < 7; ++dd) {
            const int dy = dy0 + dd;
            const unsigned int* frow = (const unsigned int*)&fr[(oy + dy) * FRSH + ox0];
            const unsigned int* krow = (const unsigned int*)&kr[dy * 32];
            unsigned int W[28], K[16], V[25];
            #pragma unroll
            for (int u = 0; u < 7; ++u) {
                uint4 v = *(const uint4*)(frow + 4 * u);
                W[4*u] = v.x; W[4*u+1] = v.y; W[4*u+2] = v.z; W[4*u+3] = v.w;
            }
            #pragma unroll
            for (int u = 0; u < 4; ++u) {
                uint4 v = *(const uint4*)(krow + 4 * u);
                K[4*u] = v.x; K[4*u+1] = v.y; K[4*u+2] = v.z; K[4*u+3] = v.w;
            }
            #pragma unroll
            for (int i = 0; i < 25; ++i)
                V[i] = (W[i] >> 16) | (W[i + 1] << 16);
            #pragma unroll
            for (int m = 0; m < 12; ++m) {
                float ae = acc[2*m], ao = acc[2*m+1];
                #pragma unroll
                for (int i = 0; i < 14; ++i) {
                    ae = __builtin_amdgcn_fdot2(u2h(W[m + i]), u2h(K[i]), ae, false);
                    ao = __builtin_amdgcn_fdot2(u2h(V[m + i]), u2h(K[i]), ao, false);
                }
                acc[2*m] = ae; acc[2*m+1] = ao;
            }
        }
        float* cvq = &L.cv[q][oy * CVS + ox0];
        #pragma unroll
        for (int u = 0; u < 6; ++u) {
            float4 v = make_float4(acc[4*u], acc[4*u+1], acc[4*u+2], acc[4*u+3]);
            *(float4*)(cvq + 4 * u) = v;
        }
    }
    __syncthreads();

    // merge quarters + block max
    float m = -INFINITY;
    for (int p = t; p < 69 * CVS; p += 1024) {
        int ox = p - (p / CVS) * CVS;
        if (ox < CPD) {
            float v = L.cv[0][p] + L.cv[1][p] + L.cv[2][p] + L.cv[3][p];
            L.cv[0][p] = v;
            m = fmaxf(m, v);
        }
    }
    #pragma unroll
    for (int off = 32; off > 0; off >>= 1) m = fmaxf(m, __shfl_down(m, off, 64));
    int lane = t & 63, wid = t >> 6;
    if (lane == 0) red[wid] = m;
    __syncthreads();
    m = red[0];
    #pragma unroll
    for (int i = 1; i < 16; ++i) m = fmaxf(m, red[i]);

    float s = 0.f;
    ushort* eo = e_buf + (size_t)ib * KPAD;
    for (int p = t; p < 69 * CVS; p += 1024) {
        int oy = p / CVS;
        int ox = p - oy * CVS;
        if (ox < CPD) {
            float ev = __expf(L.cv[0][p] - m);
            __hip_bfloat16 h = __float2bfloat16(ev);
            eo[oy * CPD + ox] = *reinterpret_cast<ushort*>(&h);
            s += ev;
        }
    }
    #pragma unroll
    for (int off = 32; off > 0; off >>= 1) s += __shfl_down(s, off, 64);
    if (lane == 0) red[16 + wid] = s;
    __syncthreads();
    if (t == 0) {
        float tot = 0.f;
        #pragma unroll
        for (int i = 0; i < 16; ++i) tot += red[16 + i];
        inv_denom[ib] = 1.0f / tot;
    }
    if (t < KPAD - NPD) eo[NPD + t] = 0;   // zero k-padding
}

// ---------------------------------------------------------------------------
// Dispatch 1: conv(k=0) + weight-prep tail (4 x 256-thread groups).
__global__ __launch_bounds__(1024, 4) void conv0_wprep_kernel(
    const float* __restrict__ frames, const int* __restrict__ tsp,
    float* __restrict__ frameL, const float* __restrict__ ck,
    ushort* __restrict__ e_buf, float* __restrict__ inv_denom,
    const float* __restrict__ W1, const float* __restrict__ Wm1,
    const float* __restrict__ Ws1,
    ushort* __restrict__ W1T, ushort* __restrict__ WhidT)
{
    __shared__ union __align__(16) {
        ConvLds conv;
        ushort wp[4][64][65];
    } sh;
    const int t  = threadIdx.x;
    const int ib = blockIdx.x;

    conv_phase(sh.conv, 0, ib, t, frames, tsp, frameL, ck, 0.f, 0.f,
               e_buf, inv_denom);
    __syncthreads();   // conv LDS dead; reuse union for wprep

    {
        const int g  = t >> 8;          // group 0..3
        const int tt = t & 255;
        const int ln = tt & 63;
        const int lr = tt >> 6;         // 0..3
        const int b  = ib * 4 + g;      // task id, 664 used
        ushort (*tile)[65] = sh.wp[g];

        if (b < 600) {
            const int k0 = (b % 75) * 64;
            const int n0 = (b / 75) * 64;
            #pragma unroll
            for (int i = 0; i < 16; ++i) {
                int kk = k0 + lr + i * 4;
                float v = (kk < NPD) ? W1[(size_t)kk * HD + n0 + ln] : 0.f;
                __hip_bfloat16 h = __float2bfloat16(v);
                tile[lr + i * 4][ln] = *reinterpret_cast<ushort*>(&h);
            }
        } else if (b < 664) {
            const int bb = b - 600;
            const int i0 = (bb & 7) * 64;
            const int r0 = (bb >> 3) * 64;
            #pragma unroll
            for (int rep = 0; rep < 16; ++rep) {
                int i = i0 + lr + rep * 4;
                int r = r0 + ln;
                const float* srcp = (r >= 256) ? Ws1 : Wm1;
                float v = srcp[(size_t)i * 256 + (r & 255)];
                __hip_bfloat16 h = __float2bfloat16(v);
                tile[lr + rep * 4][ln] = *reinterpret_cast<ushort*>(&h);
            }
        }
        __syncthreads();
        if (b < 600) {
            const int k0 = (b % 75) * 64;
            const int n0 = (b / 75) * 64;
            #pragma unroll
            for (int i = 0; i < 16; ++i) {
                int nn = lr + i * 4;
                int kk = k0 + ln;
                if (kk < KPAD)
                    W1T[(size_t)(n0 + nn) * KPAD + kk] = tile[ln][nn];
            }
        } else if (b < 664) {
            const int bb = b - 600;
            const int i0 = (bb & 7) * 64;
            const int r0 = (bb >> 3) * 64;
            #pragma unroll
            for (int rep = 0; rep < 16; ++rep) {
                int r = r0 + lr + rep * 4;
                WhidT[(size_t)r * 512 + i0 + ln] = tile[ln][lr + rep * 4];
            }
        }
    }
}

// ---------------------------------------------------------------------------
// Cpart = E(256xKPAD bf16) @ W1T^T (KPADx512 bf16), split-K=15, MFMA.
// v2: register-direct fragment loads (no LDS, no barriers). Each wave loads
// A/B fragments straight from global in MFMA layout; B panel (4 KB/step) is
// shared by the block's 4 waves via L1. Identical math to the LDS version:
// a_lane = E[(m0 + w*16 + (l&15))*KPAD + kk + (l>>4)*8], same for W1T rows.
// Cpart layout now [m][z][n] so the MLP's split-K sum is contiguous.
__global__ __launch_bounds__(256) void gemm1_mfma(
    const ushort* __restrict__ E, const ushort* __restrict__ W1T,
    float* __restrict__ Cpart)
{
    const int t  = threadIdx.x;
    const int m0 = blockIdx.x * 64;   // 4
    const int n0 = blockIdx.y * 64;   // 8
    const int z  = blockIdx.z;        // 15
    const int step0 = z * 10;
    const int nstep = min(10, 149 - step0);   // z=14 -> 9

    const int l  = t & 63;
    const int w  = t >> 6;            // wave 0..3
    const int lm = l & 15;
    const int kb = l >> 4;            // 0..3

    f32x4 zero = {0.f, 0.f, 0.f, 0.f};
    f32x4 acc[4] = {zero, zero, zero, zero};

    const ushort* pA = E   + (size_t)(m0 + w * 16 + lm) * KPAD + kb * 8;
    const ushort* pB = W1T + (size_t)(n0 + lm) * KPAD + kb * 8;

    int kk = step0 * 32;
    bf16x8 a  = *(const bf16x8*)(pA + kk);
    bf16x8 b0 = *(const bf16x8*)(pB + kk);
    bf16x8 b1 = *(const bf16x8*)(pB + 16 * KPAD + kk);
    bf16x8 b2 = *(const bf16x8*)(pB + 32 * KPAD + kk);
    bf16x8 b3 = *(const bf16x8*)(pB + 48 * KPAD + kk);

    for (int s = 0; s < nstep; ++s) {
        bf16x8 ca = a, c0 = b0, c1 = b1, c2 = b2, c3 = b3;
        if (s + 1 < nstep) {
            kk += 32;
            a  = *(const bf16x8*)(pA + kk);
            b0 = *(const bf16x8*)(pB + kk);
            b1 = *(const bf16x8*)(pB + 16 * KPAD + kk);
            b2 = *(const bf16x8*)(pB + 32 * KPAD + kk);
            b3 = *(const bf16x8*)(pB + 48 * KPAD + kk);
        }
        acc[0] = __builtin_amdgcn_mfma_f32_16x16x32_bf16(ca, c0, acc[0], 0, 0, 0);
        acc[1] = __builtin_amdgcn_mfma_f32_16x16x32_bf16(ca, c1, acc[1], 0, 0, 0);
        acc[2] = __builtin_amdgcn_mfma_f32_16x16x32_bf16(ca, c2, acc[2], 0, 0, 0);
        acc[3] = __builtin_amdgcn_mfma_f32_16x16x32_bf16(ca, c3, acc[3], 0, 0, 0);
    }

    // C/D layout: col = lane&15 (n), row = (lane>>4)*4 + reg (m)
    const int mrow = m0 + w * 16 + kb * 4;
    #pragma unroll
    for (int j = 0; j < 4; ++j) {
        int n = n0 + j * 16 + lm;
        #pragma unroll
        for (int rg = 0; rg < 4; ++rg)
            Cpart[((size_t)(mrow + rg) * SPLITK + z) * HD + n] = acc[j][rg];
    }
}

// ---------------------------------------------------------------------------
// MLP phase (t < 512 active; verified body). Returns z via z_keep LDS.
__device__ __forceinline__ void mlp_phase(
    MlpLds& L, int km, int ib, int t,
    const float* __restrict__ Cpart, const float* __restrict__ inv_denom,
    const float* __restrict__ b1, const ushort* __restrict__ WhidT,
    const float* __restrict__ bm1, const float* __restrict__ bs1,
    const float* __restrict__ Wm2, const float* __restrict__ bm2,
    const float* __restrict__ Ws2, const float* __restrict__ bs2,
    const float* __restrict__ eps, float* __restrict__ out,
    float* z_keep)
{
    if (t < HD) {
        float s = 0.f;
        #pragma unroll
        for (int z = 0; z < SPLITK; ++z)
            s += Cpart[((size_t)ib * SPLITK + z) * HD + t];
        L.hsh[t] = fmaxf(fmaf(s, inv_denom[ib], b1[t]), 0.f);
    }
    __syncthreads();

    if (t < 512) {
        int head = t >> 8, col = t & 255;
        const uint4* Wr = (const uint4*)(WhidT + (size_t)(head * 256 + col) * 512);
        float bias = head ? bs1[col] : bm1[col];
        float a = 0.f;
        #pragma unroll 8
        for (int u = 0; u < 64; ++u) {
            uint4 wv = Wr[u];
            const float* hp = &L.hsh[u * 8];
            a = fmaf(hp[0], bf2f_lo(wv.x), a);
            a = fmaf(hp[1], bf2f_hi(wv.x), a);
            a = fmaf(hp[2], bf2f_lo(wv.y), a);
            a = fmaf(hp[3], bf2f_hi(wv.y), a);
            a = fmaf(hp[4], bf2f_lo(wv.z), a);
            a = fmaf(hp[5], bf2f_hi(wv.z), a);
            a = fmaf(hp[6], bf2f_lo(wv.w), a);
            a = fmaf(hp[7], bf2f_hi(wv.w), a);
        }
        L.h2[head][col] = fmaxf(a + bias, 0.f);
    }
    __syncthreads();

    {
        int w = t >> 6, l = t & 63;
        if (w < 4) {
            int zd = (w >> 1) & 1, head = w & 1;
            const float* W2 = head ? Ws2 : Wm2;
            float a = 0.f;
            #pragma unroll
            for (int u = 0; u < 4; ++u) {
                int i = l + u * 64;
                a = fmaf(L.h2[head][i], W2[i * 2 + zd], a);
            }
            #pragma unroll
            for (int off = 32; off > 0; off >>= 1) a += __shfl_down(a, off, 64);
            if (l == 0) {
                float r = head ? __expf(a + bs2[zd]) : tanhf(a + bm2[zd]);
                L.res_sh[zd][head] = r;
            }
        }
    }
    __syncthreads();
    if (t < 2) {
        int zd = t;
        float mean = L.res_sh[zd][0];
        float stdv = L.res_sh[zd][1];
        float ev = eps[(size_t)ib * 6 + km * 2 + zd];
        float z = fmaf(stdv, ev, mean);
        int oidx = ib * 6 + km * 2 + zd;
        out[oidx]        = mean;   // q_mean
        out[1536 + oidx] = stdv;   // q_std
        out[3072 + oidx] = z;      // z_where
        z_keep[zd] = z;            // block-local handoff to fused conv
    }
}

// ---------------------------------------------------------------------------
// Dispatch 3/5: mlp(km) + conv(km+1), fully block-local fusion.
__global__ __launch_bounds__(1024, 4) void mlp_conv_kernel(
    const float* __restrict__ Cpart, const float* __restrict__ inv_denom,
    const float* __restrict__ b1, const ushort* __restrict__ WhidT,
    const float* __restrict__ bm1, const float* __restrict__ bs1,
    const float* __restrict__ Wm2, const float* __restrict__ bm2,
    const float* __restrict__ Ws2, const float* __restrict__ bs2,
    const float* __restrict__ eps, float* __restrict__ out,
    const float* __restrict__ frames, const int* __restrict__ tsp,
    float* __restrict__ frameL, const float* __restrict__ ck,
    ushort* __restrict__ e_buf, int km)
{
    __shared__ union __align__(16) {
        ConvLds conv;
        MlpLds  mlp;
    } sh;
    __shared__ float z_keep[2];
    const int t  = threadIdx.x;
    const int ib = blockIdx.x;

    mlp_phase(sh.mlp, km, ib, t, Cpart, inv_denom, b1, WhidT,
              bm1, bs1, Wm2, bm2, Ws2, bs2, eps, out, z_keep);
    __syncthreads();   // mlp LDS dead; z_keep visible to all

    float zx = z_keep[0], zy = z_keep[1];
    conv_phase(sh.conv, km + 1, ib, t, frames, tsp, frameL, ck, zx, zy,
               e_buf, (float*)inv_denom);
}

// ---------------------------------------------------------------------------
// Dispatch 7: final mlp (km=2), standalone.
__global__ __launch_bounds__(512) void mlp_final_kernel(
    const float* __restrict__ Cpart, const float* __restrict__ inv_denom,
    const float* __restrict__ b1, const ushort* __restrict__ WhidT,
    const float* __restrict__ bm1, const float* __restrict__ bs1,
    const float* __restrict__ Wm2, const float* __restrict__ bm2,
    const float* __restrict__ Ws2, const float* __restrict__ bs2,
    const float* __restrict__ eps, float* __restrict__ out)
{
    __shared__ MlpLds L;
    __shared__ float z_keep[2];
    mlp_phase(L, 2, blockIdx.x, threadIdx.x, Cpart, inv_denom, b1, WhidT,
              bm1, bs1, Wm2, bm2, Ws2, bs2, eps, out, z_keep);
}

// ---------------------------------------------------------------------------
extern "C" void kernel_launch(void* const* d_in, const int* in_sizes, int n_in,
                              void* d_out, int out_size, void* d_ws, size_t ws_size,
                              hipStream_t stream)
{
    const float* frames = (const float*)d_in[0];
    const float* ck     = (const float*)d_in[1];
    const float* eps    = (const float*)d_in[2];
    const float* W1     = (const float*)d_in[3];
    const float* b1     = (const float*)d_in[4];
    const float* Wm1    = (const float*)d_in[5];
    const float* bm1    = (const float*)d_in[6];
    const float* Wm2    = (const float*)d_in[7];
    const float* bm2    = (const float*)d_in[8];
    const float* Ws1    = (const float*)d_in[9];
    const float* bs1    = (const float*)d_in[10];
    const float* Ws2    = (const float*)d_in[11];
    const float* bs2    = (const float*)d_in[12];
    const int*   tsp    = (const int*)d_in[13];
    float* out = (float*)d_out;

    float* frameL  = (float*)d_ws;                   // 2359296 f
    float* Cpart   = frameL + 2359296;               // 256*15*512 = 1966080 f
    float* inv_den = Cpart + 1966080;                // 256 f
    ushort* e_buf  = (ushort*)(inv_den + 256);       // 256*KPAD
    ushort* W1T    = e_buf + (size_t)SBN * KPAD;     // 512*KPAD
    ushort* WhidT  = W1T + (size_t)HD * KPAD;        // 512*512

    // D1: conv k=0 (+ wprep tail)
    conv0_wprep_kernel<<<256, 1024, 0, stream>>>(
        frames, tsp, frameL, ck, e_buf, inv_den, W1, Wm1, Ws1, W1T, WhidT);
    // D2: gemm k=0
    gemm1_mfma<<<dim3(4, 8, SPLITK), 256, 0, stream>>>(e_buf, W1T, Cpart);
    // D3: mlp k=0 + conv k=1
    mlp_conv_kernel<<<256, 1024, 0, stream>>>(
        Cpart, inv_den, b1, WhidT, bm1, bs1, Wm2, bm2, Ws2, bs2,
        eps, out, frames, tsp, frameL, ck, e_buf, 0);
    // D4: gemm k=1
    gemm1_mfma<<<dim3(4, 8, SPLITK), 256, 0, stream>>>(e_buf, W1T, Cpart);
    // D5: mlp k=1 + conv k=2
    mlp_conv_kernel<<<256, 1024, 0, stream>>>(
        Cpart, inv_den, b1, WhidT, bm1, bs1, Wm2, bm2, Ws2, bs2,
        eps, out, frames, tsp, frameL, ck, e_buf, 1);
    // D6: gemm k=2
    gemm1_mfma<<<dim3(4, 8, SPLITK), 256, 0, stream>>>(e_buf, W1T, Cpart);
    // D7: mlp k=2
    mlp_final_kernel<<<256, 512, 0, stream>>>(
        Cpart, inv_den, b1, WhidT, bm1, bs1, Wm2, bm2, Ws2, bs2, eps, out);
}

// Round 5
// 298.558 us; speedup vs baseline: 1.0273x; 1.0273x over previous
//
#include <hip/hip_runtime.h>
#include <hip/hip_bf16.h>
#include <math.h>

// Problem constants
#define FPD 96      // frame size
#define DPD 28      // digit/kernel size
#define CPD 69      // FPD - DPD + 1
#define NPD 4761    // CPD*CPD
#define KKC 3       // K iterations
#define SBN 256     // S*B images
#define TT 8        // T
#define HD 512      // H
#define ZDD 2
#define KPAD 4768   // 149*32, padded K for MFMA GEMM
#define SPLITK 15
#define FRSH 104    // frame LDS row stride (halfs): 52 words, mod32=20 -> conflict-free
#define CVS 76      // cv slab row stride (floats): mod32=12 -> conflict-free

typedef __attribute__((ext_vector_type(8))) short bf16x8;
typedef __attribute__((ext_vector_type(4))) float f32x4;
typedef _Float16 half_t;
typedef __attribute__((ext_vector_type(2))) _Float16 half2_t;

__device__ __forceinline__ float bf2f_lo(unsigned int u) {
    union { unsigned int i; float f; } v; v.i = u << 16; return v.f;
}
__device__ __forceinline__ float bf2f_hi(unsigned int u) {
    union { unsigned int i; float f; } v; v.i = u & 0xffff0000u; return v.f;
}
__device__ __forceinline__ half2_t u2h(unsigned int u) {
    union { unsigned int i; half2_t h; } v; v.i = u; return v.h;
}

// Conv-phase LDS block (~106.4 KB -> 1 block/CU for kernels containing it).
// NOTE: kr/dg live at byte offsets >= 19968, disjoint from MlpLds (< 4200),
// so they can be staged BEFORE the MLP phase runs in the union.
struct ConvLds {
    half_t fr[96 * FRSH];
    half_t kr[28 * 32];   // rows padded to 32 halfs
    float  dg[784];
    float  cv[4][69 * CVS];
    float  red[32];
};

struct MlpLds {
    float hsh[HD];
    float h2[2][256];
    float res_sh[2][2];
};

// ---------------------------------------------------------------------------
// Conv body AFTER the frame values are already in registers (pf[9]) and
// kr/dg are already staged in LDS (with >=1 barrier since the stage).
// Identical math to the verified 301us baseline conv.
__device__ __forceinline__ void conv_rest(
    ConvLds& L, int k, int ib, int t,
    const float* __restrict__ pf,
    float* __restrict__ frameL,
    float zx, float zy,
    ushort* __restrict__ e_buf, float* __restrict__ inv_denom)
{
    half_t* fr  = L.fr;
    half_t* kr  = L.kr;
    float*  dg  = L.dg;
    float*  red = L.red;

    const float scale = 96.f / 28.f;
    #pragma unroll
    for (int i = 0; i < 9; ++i) {
        int p = t + i * 1024;
        int r = p / 96, c = p - r * 96;
        float val = pf[i];
        if (k > 0) {
            float oci = (2.f * r + 1.f) / 96.f - 1.f;
            float ocj = (2.f * c + 1.f) / 96.f - 1.f;
            float py = ((scale * (oci - zy) + 1.f) * 28.f - 1.f) * 0.5f;
            float px = ((scale * (ocj - zx) + 1.f) * 28.f - 1.f) * 0.5f;
            float py0f = floorf(py), px0f = floorf(px);
            float fy = py - py0f, fx = px - px0f;
            int y0 = (int)py0f, x0 = (int)px0f;
            int y1 = y0 + 1, x1 = x0 + 1;
            float wy0 = (y0 >= 0 && y0 < DPD) ? 1.f - fy : 0.f;
            float wy1 = (y1 >= 0 && y1 < DPD) ? fy : 0.f;
            float wx0 = (x0 >= 0 && x0 < DPD) ? 1.f - fx : 0.f;
            float wx1 = (x1 >= 0 && x1 < DPD) ? fx : 0.f;
            int y0c = min(max(y0, 0), DPD - 1), y1c = min(max(y1, 0), DPD - 1);
            int x0c = min(max(x0, 0), DPD - 1), x1c = min(max(x1, 0), DPD - 1);
            float tmp0 = wy0 * dg[y0c * DPD + x0c] + wy1 * dg[y1c * DPD + x0c];
            float tmp1 = wy0 * dg[y0c * DPD + x1c] + wy1 * dg[y1c * DPD + x1c];
            val -= wx0 * tmp0 + wx1 * tmp1;
        }
        fr[r * FRSH + c] = (half_t)val;
        if (k == 1) frameL[(size_t)ib * 9216 + p] = val;
    }
    if (t < 96 * 8) fr[(t >> 3) * FRSH + 96 + (t & 7)] = (half_t)0.f; // pad cols
    __syncthreads();

    if (t < 828) {
        const int q    = t / 207;
        const int rem  = t - q * 207;
        const int tile = rem / 69;
        const int oy   = rem - tile * 69;
        const int ox0  = tile * 24;
        const int dy0  = q * 7;

        float acc[24];
        #pragma unroll
        for (int j = 0; j < 24; ++j) acc[j] = 0.f;

        #pragma unroll 1
        for (int dd = 0; dd < 7; ++dd) {
            const int dy = dy0 + dd;
            const unsigned int* frow = (const unsigned int*)&fr[(oy + dy) * FRSH + ox0];
            const unsigned int* krow = (const unsigned int*)&kr[dy * 32];
            unsigned int W[28], K[16], V[25];
            #pragma unroll
            for (int u = 0; u < 7; ++u) {
                uint4 v = *(const uint4*)(frow + 4 * u);
                W[4*u] = v.x; W[4*u+1] = v.y; W[4*u+2] = v.z; W[4*u+3] = v.w;
            }
            #pragma unroll
            for (int u = 0; u < 4; ++u) {
                uint4 v = *(const uint4*)(krow + 4 * u);
                K[4*u] = v.x; K[4*u+1] = v.y; K[4*u+2] = v.z; K[4*u+3] = v.w;
            }
            #pragma unroll
            for (int i = 0; i < 25; ++i)
                V[i] = (W[i] >> 16) | (W[i + 1] << 16);
            #pragma unroll
            for (int m = 0; m < 12; ++m) {
                float ae = acc[2*m], ao = acc[2*m+1];
                #pragma unroll
                for (int i = 0; i < 14; ++i) {
                    ae = __builtin_amdgcn_fdot2(u2h(W[m + i]), u2h(K[i]), ae, false);
                    ao = __builtin_amdgcn_fdot2(u2h(V[m + i]), u2h(K[i]), ao, false);
                }
                acc[2*m] = ae; acc[2*m+1] = ao;
            }
        }
        float* cvq = &L.cv[q][oy * CVS + ox0];
        #pragma unroll
        for (int u = 0; u < 6; ++u) {
            float4 v = make_float4(acc[4*u], acc[4*u+1], acc[4*u+2], acc[4*u+3]);
            *(float4*)(cvq + 4 * u) = v;
        }
    }
    __syncthreads();

    // merge quarters + block max
    float m = -INFINITY;
    for (int p = t; p < 69 * CVS; p += 1024) {
        int ox = p - (p / CVS) * CVS;
        if (ox < CPD) {
            float v = L.cv[0][p] + L.cv[1][p] + L.cv[2][p] + L.cv[3][p];
            L.cv[0][p] = v;
            m = fmaxf(m, v);
        }
    }
    #pragma unroll
    for (int off = 32; off > 0; off >>= 1) m = fmaxf(m, __shfl_down(m, off, 64));
    int lane = t & 63, wid = t >> 6;
    if (lane == 0) red[wid] = m;
    __syncthreads();
    m = red[0];
    #pragma unroll
    for (int i = 1; i < 16; ++i) m = fmaxf(m, red[i]);

    float s = 0.f;
    ushort* eo = e_buf + (size_t)ib * KPAD;
    for (int p = t; p < 69 * CVS; p += 1024) {
        int oy = p / CVS;
        int ox = p - oy * CVS;
        if (ox < CPD) {
            float ev = __expf(L.cv[0][p] - m);
            __hip_bfloat16 h = __float2bfloat16(ev);
            eo[oy * CPD + ox] = *reinterpret_cast<ushort*>(&h);
            s += ev;
        }
    }
    #pragma unroll
    for (int off = 32; off > 0; off >>= 1) s += __shfl_down(s, off, 64);
    if (lane == 0) red[16 + wid] = s;
    __syncthreads();
    if (t == 0) {
        float tot = 0.f;
        #pragma unroll
        for (int i = 0; i < 16; ++i) tot += red[16 + i];
        inv_denom[ib] = 1.0f / tot;
    }
    if (t < KPAD - NPD) eo[NPD + t] = 0;   // zero k-padding
}

// ---------------------------------------------------------------------------
// MLP phase; csum (split-K sum), bias and inv_denom are prefetched by caller.
__device__ __forceinline__ void mlp_phase(
    MlpLds& L, int km, int ib, int t,
    float csum, float invd, float b1v,
    const ushort* __restrict__ WhidT,
    const float* __restrict__ bm1, const float* __restrict__ bs1,
    const float* __restrict__ Wm2, const float* __restrict__ bm2,
    const float* __restrict__ Ws2, const float* __restrict__ bs2,
    const float* __restrict__ eps, float* __restrict__ out,
    float* z_keep)
{
    if (t < HD)
        L.hsh[t] = fmaxf(fmaf(csum, invd, b1v), 0.f);
    __syncthreads();

    if (t < 512) {
        int head = t >> 8, col = t & 255;
        const uint4* Wr = (const uint4*)(WhidT + (size_t)(head * 256 + col) * 512);
        float bias = head ? bs1[col] : bm1[col];
        float a = 0.f;
        #pragma unroll 8
        for (int u = 0; u < 64; ++u) {
            uint4 wv = Wr[u];
            const float* hp = &L.hsh[u * 8];
            a = fmaf(hp[0], bf2f_lo(wv.x), a);
            a = fmaf(hp[1], bf2f_hi(wv.x), a);
            a = fmaf(hp[2], bf2f_lo(wv.y), a);
            a = fmaf(hp[3], bf2f_hi(wv.y), a);
            a = fmaf(hp[4], bf2f_lo(wv.z), a);
            a = fmaf(hp[5], bf2f_hi(wv.z), a);
            a = fmaf(hp[6], bf2f_lo(wv.w), a);
            a = fmaf(hp[7], bf2f_hi(wv.w), a);
        }
        L.h2[head][col] = fmaxf(a + bias, 0.f);
    }
    __syncthreads();

    {
        int w = t >> 6, l = t & 63;
        if (w < 4) {
            int zd = (w >> 1) & 1, head = w & 1;
            const float* W2 = head ? Ws2 : Wm2;
            float a = 0.f;
            #pragma unroll
            for (int u = 0; u < 4; ++u) {
                int i = l + u * 64;
                a = fmaf(L.h2[head][i], W2[i * 2 + zd], a);
            }
            #pragma unroll
            for (int off = 32; off > 0; off >>= 1) a += __shfl_down(a, off, 64);
            if (l == 0) {
                float r = head ? __expf(a + bs2[zd]) : tanhf(a + bm2[zd]);
                L.res_sh[zd][head] = r;
            }
        }
    }
    __syncthreads();
    if (t < 2) {
        int zd = t;
        float mean = L.res_sh[zd][0];
        float stdv = L.res_sh[zd][1];
        float ev = eps[(size_t)ib * 6 + km * 2 + zd];
        float z = fmaf(stdv, ev, mean);
        int oidx = ib * 6 + km * 2 + zd;
        out[oidx]        = mean;   // q_mean
        out[1536 + oidx] = stdv;   // q_std
        out[3072 + oidx] = z;      // z_where
        z_keep[zd] = z;            // block-local handoff to fused conv
    }
}

// ---------------------------------------------------------------------------
// Dispatch 1: conv(k=0) + weight-prep tail.
// Frame loads issued at the very top (overlap HBM latency with kr staging).
__global__ __launch_bounds__(1024, 4) void conv0_wprep_kernel(
    const float* __restrict__ frames, const int* __restrict__ tsp,
    float* __restrict__ frameL, const float* __restrict__ ck,
    ushort* __restrict__ e_buf, float* __restrict__ inv_denom,
    const float* __restrict__ W1, const float* __restrict__ Wm1,
    const float* __restrict__ Ws1,
    ushort* __restrict__ W1T, ushort* __restrict__ WhidT)
{
    __shared__ union __align__(16) {
        ConvLds conv;
        ushort wp[4][64][65];
    } sh;
    const int t  = threadIdx.x;
    const int ib = blockIdx.x;

    // ---- prefetch: frame -> regs, kernel row -> LDS (no barrier needed:
    // kr is consumed only after conv_rest's first barrier) ----
    const float* src = frames + ((size_t)ib * TT + *tsp) * 9216;
    float pf[9];
    #pragma unroll
    for (int i = 0; i < 9; ++i) pf[i] = src[t + i * 1024];
    if (t < 28 * 32) {
        int dy = t >> 5, dx = t & 31;
        float v = (dx < 28) ? ck[((size_t)ib * KKC + 0) * 784 + dy * 28 + dx] : 0.f;
        sh.conv.kr[t] = (half_t)v;
    }

    conv_rest(sh.conv, 0, ib, t, pf, frameL, 0.f, 0.f, e_buf, inv_denom);
    __syncthreads();   // conv LDS dead; reuse union for wprep

    {
        const int g  = t >> 8;          // group 0..3
        const int tt = t & 255;
        const int ln = tt & 63;
        const int lr = tt >> 6;         // 0..3
        const int b  = ib * 4 + g;      // task id, 664 used
        ushort (*tile)[65] = sh.wp[g];

        if (b < 600) {
            const int k0 = (b % 75) * 64;
            const int n0 = (b / 75) * 64;
            #pragma unroll
            for (int i = 0; i < 16; ++i) {
                int kk = k0 + lr + i * 4;
                float v = (kk < NPD) ? W1[(size_t)kk * HD + n0 + ln] : 0.f;
                __hip_bfloat16 h = __float2bfloat16(v);
                tile[lr + i * 4][ln] = *reinterpret_cast<ushort*>(&h);
            }
        } else if (b < 664) {
            const int bb = b - 600;
            const int i0 = (bb & 7) * 64;
            const int r0 = (bb >> 3) * 64;
            #pragma unroll
            for (int rep = 0; rep < 16; ++rep) {
                int i = i0 + lr + rep * 4;
                int r = r0 + ln;
                const float* srcp = (r >= 256) ? Ws1 : Wm1;
                float v = srcp[(size_t)i * 256 + (r & 255)];
                __hip_bfloat16 h = __float2bfloat16(v);
                tile[lr + rep * 4][ln] = *reinterpret_cast<ushort*>(&h);
            }
        }
        __syncthreads();
        if (b < 600) {
            const int k0 = (b % 75) * 64;
            const int n0 = (b / 75) * 64;
            #pragma unroll
            for (int i = 0; i < 16; ++i) {
                int nn = lr + i * 4;
                int kk = k0 + ln;
                if (kk < KPAD)
                    W1T[(size_t)(n0 + nn) * KPAD + kk] = tile[ln][nn];
            }
        } else if (b < 664) {
            const int bb = b - 600;
            const int i0 = (bb & 7) * 64;
            const int r0 = (bb >> 3) * 64;
            #pragma unroll
            for (int rep = 0; rep < 16; ++rep) {
                int r = r0 + lr + rep * 4;
                WhidT[(size_t)r * 512 + i0 + ln] = tile[ln][lr + rep * 4];
            }
        }
    }
}

// ---------------------------------------------------------------------------
// Cpart = E @ W1T^T, split-K=15, MFMA, register-direct (no LDS/barriers).
// Cpart layout [m][z][n] so the MLP split-K sum is contiguous.
__global__ __launch_bounds__(256) void gemm1_mfma(
    const ushort* __restrict__ E, const ushort* __restrict__ W1T,
    float* __restrict__ Cpart)
{
    const int t  = threadIdx.x;
    const int m0 = blockIdx.x * 64;   // 4
    const int n0 = blockIdx.y * 64;   // 8
    const int z  = blockIdx.z;        // 15
    const int step0 = z * 10;
    const int nstep = min(10, 149 - step0);   // z=14 -> 9

    const int l  = t & 63;
    const int w  = t >> 6;            // wave 0..3
    const int lm = l & 15;
    const int kb = l >> 4;            // 0..3

    f32x4 zero = {0.f, 0.f, 0.f, 0.f};
    f32x4 acc[4] = {zero, zero, zero, zero};

    const ushort* pA = E   + (size_t)(m0 + w * 16 + lm) * KPAD + kb * 8;
    const ushort* pB = W1T + (size_t)(n0 + lm) * KPAD + kb * 8;

    int kk = step0 * 32;
    bf16x8 a  = *(const bf16x8*)(pA + kk);
    bf16x8 b0 = *(const bf16x8*)(pB + kk);
    bf16x8 b1 = *(const bf16x8*)(pB + 16 * KPAD + kk);
    bf16x8 b2 = *(const bf16x8*)(pB + 32 * KPAD + kk);
    bf16x8 b3 = *(const bf16x8*)(pB + 48 * KPAD + kk);

    for (int s = 0; s < nstep; ++s) {
        bf16x8 ca = a, c0 = b0, c1 = b1, c2 = b2, c3 = b3;
        if (s + 1 < nstep) {
            kk += 32;
            a  = *(const bf16x8*)(pA + kk);
            b0 = *(const bf16x8*)(pB + kk);
            b1 = *(const bf16x8*)(pB + 16 * KPAD + kk);
            b2 = *(const bf16x8*)(pB + 32 * KPAD + kk);
            b3 = *(const bf16x8*)(pB + 48 * KPAD + kk);
        }
        acc[0] = __builtin_amdgcn_mfma_f32_16x16x32_bf16(ca, c0, acc[0], 0, 0, 0);
        acc[1] = __builtin_amdgcn_mfma_f32_16x16x32_bf16(ca, c1, acc[1], 0, 0, 0);
        acc[2] = __builtin_amdgcn_mfma_f32_16x16x32_bf16(ca, c2, acc[2], 0, 0, 0);
        acc[3] = __builtin_amdgcn_mfma_f32_16x16x32_bf16(ca, c3, acc[3], 0, 0, 0);
    }

    // C/D layout: col = lane&15 (n), row = (lane>>4)*4 + reg (m)
    const int mrow = m0 + w * 16 + kb * 4;
    #pragma unroll
    for (int j = 0; j < 4; ++j) {
        int n = n0 + j * 16 + lm;
        #pragma unroll
        for (int rg = 0; rg < 4; ++rg)
            Cpart[((size_t)(mrow + rg) * SPLITK + z) * HD + n] = acc[j][rg];
    }
}

// ---------------------------------------------------------------------------
// Dispatch 3/5: mlp(km) + conv(km+1), block-local fusion with full prefetch:
// frame regs + kr/dg LDS staged BEFORE the MLP phase (latency hidden under
// MLP compute); kr/dg LDS region (>=19968B) is disjoint from MlpLds (<4200B).
__global__ __launch_bounds__(1024, 4) void mlp_conv_kernel(
    const float* __restrict__ Cpart, const float* __restrict__ inv_denom,
    const float* __restrict__ b1, const ushort* __restrict__ WhidT,
    const float* __restrict__ bm1, const float* __restrict__ bs1,
    const float* __restrict__ Wm2, const float* __restrict__ bm2,
    const float* __restrict__ Ws2, const float* __restrict__ bs2,
    const float* __restrict__ eps, float* __restrict__ out,
    const float* __restrict__ frames, const int* __restrict__ tsp,
    float* __restrict__ frameL, const float* __restrict__ ck,
    ushort* __restrict__ e_buf, int km)
{
    __shared__ union __align__(16) {
        ConvLds conv;
        MlpLds  mlp;
    } sh;
    __shared__ float z_keep[2];
    const int t  = threadIdx.x;
    const int ib = blockIdx.x;
    const int k  = km + 1;            // conv iteration (1 or 2)

    // ---- prefetch phase (all inputs ready at kernel entry) ----
    // frame -> registers
    const float* src = (k < 2)
        ? frames + ((size_t)ib * TT + *tsp) * 9216
        : frameL + (size_t)ib * 9216;
    float pf[9];
    #pragma unroll
    for (int i = 0; i < 9; ++i) pf[i] = src[t + i * 1024];
    // conv kernel row + prev digit -> LDS (disjoint from MLP's LDS region;
    // MLP's internal barriers order these stores before conv consumes them)
    if (t < 28 * 32) {
        int dy = t >> 5, dx = t & 31;
        float v = (dx < 28) ? ck[((size_t)ib * KKC + k) * 784 + dy * 28 + dx] : 0.f;
        sh.conv.kr[t] = (half_t)v;
    }
    if (t < 784) sh.conv.dg[t] = ck[((size_t)ib * KKC + (k - 1)) * 784 + t];
    // MLP inputs: split-K sum + bias + inv_denom
    float csum = 0.f, b1v = 0.f;
    if (t < HD) {
        #pragma unroll
        for (int z = 0; z < SPLITK; ++z)
            csum += Cpart[((size_t)ib * SPLITK + z) * HD + t];
        b1v = b1[t];
    }
    float invd = inv_denom[ib];

    // ---- MLP (uses only MlpLds region) ----
    mlp_phase(sh.mlp, km, ib, t, csum, invd, b1v, WhidT,
              bm1, bs1, Wm2, bm2, Ws2, bs2, eps, out, z_keep);
    __syncthreads();   // mlp LDS dead; z_keep visible to all

    float zx = z_keep[0], zy = z_keep[1];
    conv_rest(sh.conv, k, ib, t, pf, frameL, zx, zy,
              e_buf, (float*)inv_denom);
}

// ---------------------------------------------------------------------------
// Dispatch 7: final mlp (km=2), standalone.
__global__ __launch_bounds__(512) void mlp_final_kernel(
    const float* __restrict__ Cpart, const float* __restrict__ inv_denom,
    const float* __restrict__ b1, const ushort* __restrict__ WhidT,
    const float* __restrict__ bm1, const float* __restrict__ bs1,
    const float* __restrict__ Wm2, const float* __restrict__ bm2,
    const float* __restrict__ Ws2, const float* __restrict__ bs2,
    const float* __restrict__ eps, float* __restrict__ out)
{
    __shared__ MlpLds L;
    __shared__ float z_keep[2];
    const int t  = threadIdx.x;
    const int ib = blockIdx.x;
    float csum = 0.f, b1v = 0.f;
    if (t < HD) {
        #pragma unroll
        for (int z = 0; z < SPLITK; ++z)
            csum += Cpart[((size_t)ib * SPLITK + z) * HD + t];
        b1v = b1[t];
    }
    float invd = inv_denom[ib];
    mlp_phase(L, 2, ib, t, csum, invd, b1v, WhidT,
              bm1, bs1, Wm2, bm2, Ws2, bs2, eps, out, z_keep);
}

// ---------------------------------------------------------------------------
extern "C" void kernel_launch(void* const* d_in, const int* in_sizes, int n_in,
                              void* d_out, int out_size, void* d_ws, size_t ws_size,
                              hipStream_t stream)
{
    const float* frames = (const float*)d_in[0];
    const float* ck     = (const float*)d_in[1];
    const float* eps    = (const float*)d_in[2];
    const float* W1     = (const float*)d_in[3];
    const float* b1     = (const float*)d_in[4];
    const float* Wm1    = (const float*)d_in[5];
    const float* bm1    = (const float*)d_in[6];
    const float* Wm2    = (const float*)d_in[7];
    const float* bm2    = (const float*)d_in[8];
    const float* Ws1    = (const float*)d_in[9];
    const float* bs1    = (const float*)d_in[10];
    const float* Ws2    = (const float*)d_in[11];
    const float* bs2    = (const float*)d_in[12];
    const int*   tsp    = (const int*)d_in[13];
    float* out = (float*)d_out;

    float* frameL  = (float*)d_ws;                   // 2359296 f
    float* Cpart   = frameL + 2359296;               // 256*15*512 = 1966080 f
    float* inv_den = Cpart + 1966080;                // 256 f
    ushort* e_buf  = (ushort*)(inv_den + 256);       // 256*KPAD
    ushort* W1T    = e_buf + (size_t)SBN * KPAD;     // 512*KPAD
    ushort* WhidT  = W1T + (size_t)HD * KPAD;        // 512*512

    // D1: conv k=0 (+ wprep tail)
    conv0_wprep_kernel<<<256, 1024, 0, stream>>>(
        frames, tsp, frameL, ck, e_buf, inv_den, W1, Wm1, Ws1, W1T, WhidT);
    // D2: gemm k=0
    gemm1_mfma<<<dim3(4, 8, SPLITK), 256, 0, stream>>>(e_buf, W1T, Cpart);
    // D3: mlp k=0 + conv k=1
    mlp_conv_kernel<<<256, 1024, 0, stream>>>(
        Cpart, inv_den, b1, WhidT, bm1, bs1, Wm2, bm2, Ws2, bs2,
        eps, out, frames, tsp, frameL, ck, e_buf, 0);
    // D4: gemm k=1
    gemm1_mfma<<<dim3(4, 8, SPLITK), 256, 0, stream>>>(e_buf, W1T, Cpart);
    // D5: mlp k=1 + conv k=2
    mlp_conv_kernel<<<256, 1024, 0, stream>>>(
        Cpart, inv_den, b1, WhidT, bm1, bs1, Wm2, bm2, Ws2, bs2,
        eps, out, frames, tsp, frameL, ck, e_buf, 1);
    // D6: gemm k=2
    gemm1_mfma<<<dim3(4, 8, SPLITK), 256, 0, stream>>>(e_buf, W1T, Cpart);
    // D7: mlp k=2
    mlp_final_kernel<<<256, 512, 0, stream>>>(
        Cpart, inv_den, b1, WhidT, bm1, bs1, Wm2, bm2, Ws2, bs2, eps, out);
}